// Round 11
// baseline (79.988 us; speedup 1.0000x reference)
//
#include <hip/hip_runtime.h>

// Malvar-He-Cutler demosaic, RGGB, reflect-101, fp32.
// Lane-dense 4px/thread + shuffle halo + factorized sums + NT stores (R10)
// + ROW-PAIR per block: 6 input rows shared by 2 output rows (y0 even, y0+1).
// Halves block count (drain pipelining), -40% redundant L2 reads, kills the
// y-parity branch. NT stores bypass LLC allocation — valid because each wave
// store fully covers its 128B lines (lane-dense); half-dense NT amplifies
// writes 1.5x (measured R5) — do not reintroduce.

typedef float f4 __attribute__((ext_vector_type(4)));

__device__ __forceinline__ int reflect_idx(int i, int n) {
    // jnp.pad mode='reflect': -1 -> 1, -2 -> 2, n -> n-2, n+1 -> n-3
    if (i < 0) i = -i;
    if (i >= n) i = 2 * n - 2 - i;
    return i;
}

__device__ __forceinline__ float clip01(float x) {
    return fminf(fmaxf(x, 0.0f), 1.0f);
}

struct Halo { float m2, m1, p4, p5; };

// cols {x0-2, x0-1, x0+4, x0+5} for array x (lane owns cols x0..x0+3)
__device__ __forceinline__ Halo make_halo(f4 x, f4 xl, f4 xr,
                                          bool lane0, bool lane63,
                                          bool ledge, bool redge) {
    Halo h;
    h.m2 = __shfl_up(x.z, 1);
    h.m1 = __shfl_up(x.w, 1);
    if (lane0) { h.m2 = xl.z; h.m1 = xl.w; }
    if (ledge) { h.m2 = x.z;  h.m1 = x.y; }   // col -2 -> 2, -1 -> 1
    h.p4 = __shfl_down(x.x, 1);
    h.p5 = __shfl_down(x.y, 1);
    if (lane63) { h.p4 = xr.x; h.p5 = xr.y; }
    if (redge)  { h.p4 = x.z;  h.p5 = x.y; }  // col W -> W-2, W+1 -> W-3
    return h;
}

template <bool EVEN_ROW>
__device__ __forceinline__ void compute4(
    const float C[8], const float S13[8], const float S04[8],
    float r[4], float g[4], float b[4]) {
#pragma unroll
    for (int k = 0; k < 4; k += 2) {
        const int c = 2 + k, o = 3 + k;
        const int ce = EVEN_ROW ? c : o;   // R/B raw-sample column
        const int co = EVEN_ROW ? o : c;   // G raw-sample column
        const float t2 = S04[ce] + C[ce - 2] + C[ce + 2];
        const float gatrb = 0.5f * C[ce]
                          + 0.25f * (S13[ce] + C[ce - 1] + C[ce + 1])
                          - 0.125f * t2;
        const float brv   = 0.75f * C[ce]
                          + 0.25f * (S13[ce - 1] + S13[ce + 1])
                          - 0.1875f * t2;
        const float t4 = C[co - 1] + C[co + 1];
        const float t5 = S13[co - 1] + S13[co + 1];
        const float t6 = C[co - 2] + C[co + 2];
        const float colv = 0.625f * C[co] + 0.5f * t4
                         - 0.125f * (t5 + t6) + 0.0625f * S04[co];
        const float rowv = 0.625f * C[co] + 0.5f * S13[co]
                         - 0.125f * t5 - 0.125f * S04[co] + 0.0625f * t6;
        if (EVEN_ROW) {
            r[k] = C[c];      g[k] = gatrb;      b[k] = brv;      // R site
            r[k + 1] = colv;  g[k + 1] = C[o];   b[k + 1] = rowv; // Gr site
        } else {
            r[k] = rowv;      g[k] = C[c];       b[k] = colv;     // Gb site
            r[k + 1] = brv;   g[k + 1] = gatrb;  b[k + 1] = C[o]; // B site
        }
    }
}

// one output row: build halos, compute 4 px, 3 NT plane-stores
template <bool EVEN_ROW>
__device__ __forceinline__ void do_row(
    f4 Cc, f4 S13, f4 S04,
    f4 LC, f4 LS13, f4 LS04, f4 RC, f4 RS13, f4 RS04,
    bool lane0, bool lane63, bool ledge, bool redge,
    float* __restrict__ o, size_t plane) {
    const Halo hC  = make_halo(Cc,  LC,  RC,  lane0, lane63, ledge, redge);
    const Halo h13 = make_halo(S13, LS13, RS13, lane0, lane63, ledge, redge);
    const Halo h04 = make_halo(S04, LS04, RS04, lane0, lane63, ledge, redge);

    const float Cw[8]  = {hC.m2,  hC.m1,  Cc.x,  Cc.y,  Cc.z,  Cc.w,  hC.p4,  hC.p5};
    const float W13[8] = {h13.m2, h13.m1, S13.x, S13.y, S13.z, S13.w, h13.p4, h13.p5};
    const float W04[8] = {h04.m2, h04.m1, S04.x, S04.y, S04.z, S04.w, h04.p4, h04.p5};

    float r[4], g[4], b[4];
    compute4<EVEN_ROW>(Cw, W13, W04, r, g, b);

    f4 vr = {clip01(r[0]), clip01(r[1]), clip01(r[2]), clip01(r[3])};
    f4 vg = {clip01(g[0]), clip01(g[1]), clip01(g[2]), clip01(g[3])};
    f4 vb = {clip01(b[0]), clip01(b[1]), clip01(b[2]), clip01(b[3])};
    __builtin_nontemporal_store(vr, (f4*)(o));
    __builtin_nontemporal_store(vg, (f4*)(o + plane));
    __builtin_nontemporal_store(vb, (f4*)(o + 2 * plane));
}

__global__ __launch_bounds__(256, 4) void demosaic_kernel(
    const float* __restrict__ bayer, float* __restrict__ out, int H, int W) {
    // XCD-chunked swizzle (gridDim.x divisible by 8)
    const int bid = blockIdx.x;
    const int chunk = gridDim.x >> 3;
    const int lin = (bid & 7) * chunk + (bid >> 3);
    const int XT = W >> 10;                 // 1024-px x-tiles per row
    const int xt = lin % XT;
    const int rowlin = lin / XT;
    const int Hp = H >> 1;
    const int y0 = (rowlin % Hp) << 1;      // even output row
    const int img = rowlin / Hp;

    const int tid = (int)threadIdx.x;
    const int lane = tid & 63;
    const bool lane0 = (lane == 0), lane63 = (lane == 63);
    const int x0 = xt * 1024 + (tid << 2);  // 4 px per thread, lane-dense
    const bool ledge = (x0 == 0);
    const bool redge = (x0 + 4 == W);

    const size_t plane = (size_t)H * W;
    const float* src = bayer + (size_t)img * plane;

    // input rows y0-2 .. y0+3
    const float* rows[6];
#pragma unroll
    for (int i = 0; i < 6; ++i)
        rows[i] = src + (size_t)reflect_idx(y0 - 2 + i, H) * W;

    f4 a0 = *(const f4*)(rows[0] + x0);
    f4 a1 = *(const f4*)(rows[1] + x0);
    f4 a2 = *(const f4*)(rows[2] + x0);
    f4 a3 = *(const f4*)(rows[3] + x0);
    f4 a4 = *(const f4*)(rows[4] + x0);
    f4 a5 = *(const f4*)(rows[5] + x0);

    // wave-edge halo composites for both output rows (predicated)
    f4 LCe = {0,0,0,0}, LS13e = {0,0,0,0}, LS04e = {0,0,0,0};
    f4 LCo = {0,0,0,0}, LS13o = {0,0,0,0}, LS04o = {0,0,0,0};
    f4 RCe = {0,0,0,0}, RS13e = {0,0,0,0}, RS04e = {0,0,0,0};
    f4 RCo = {0,0,0,0}, RS13o = {0,0,0,0}, RS04o = {0,0,0,0};
    if (lane0 && !ledge) {
        f4 l0 = *(const f4*)(rows[0] + x0 - 4);
        f4 l1 = *(const f4*)(rows[1] + x0 - 4);
        f4 l2 = *(const f4*)(rows[2] + x0 - 4);
        f4 l3 = *(const f4*)(rows[3] + x0 - 4);
        f4 l4 = *(const f4*)(rows[4] + x0 - 4);
        f4 l5 = *(const f4*)(rows[5] + x0 - 4);
        LCe = l2; LS13e = l1 + l3; LS04e = l0 + l4;
        LCo = l3; LS13o = l2 + l4; LS04o = l1 + l5;
    }
    if (lane63 && !redge) {
        f4 r0 = *(const f4*)(rows[0] + x0 + 4);
        f4 r1 = *(const f4*)(rows[1] + x0 + 4);
        f4 r2 = *(const f4*)(rows[2] + x0 + 4);
        f4 r3 = *(const f4*)(rows[3] + x0 + 4);
        f4 r4 = *(const f4*)(rows[4] + x0 + 4);
        f4 r5 = *(const f4*)(rows[5] + x0 + 4);
        RCe = r2; RS13e = r1 + r3; RS04e = r0 + r4;
        RCo = r3; RS13o = r2 + r4; RS04o = r1 + r5;
    }

    float* o = out + (size_t)img * 3 * plane + (size_t)y0 * W + x0;

    // even row y0: C=a2, S13=a1+a3, S04=a0+a4
    do_row<true>(a2, a1 + a3, a0 + a4,
                 LCe, LS13e, LS04e, RCe, RS13e, RS04e,
                 lane0, lane63, ledge, redge, o, plane);
    // odd row y0+1: C=a3, S13=a2+a4, S04=a1+a5
    do_row<false>(a3, a2 + a4, a1 + a5,
                  LCo, LS13o, LS04o, RCo, RS13o, RS04o,
                  lane0, lane63, ledge, redge, o + W, plane);
}

extern "C" void kernel_launch(void* const* d_in, const int* in_sizes, int n_in,
                              void* d_out, int out_size, void* d_ws, size_t ws_size,
                              hipStream_t stream) {
    const float* bayer = (const float*)d_in[0];
    float* out = (float*)d_out;

    const int H = 2048, W = 2048;
    const int B = in_sizes[0] / (H * W);
    const int XT = W >> 10;  // 1024-px x-tiles

    dim3 block(256, 1, 1);
    dim3 grid(B * (H >> 1) * XT, 1, 1);  // one block per row pair per x-tile
    demosaic_kernel<<<grid, block, 0, stream>>>(bayer, out, H, W);
}

// Round 12
// 75.774 us; speedup vs baseline: 1.0556x; 1.0556x over previous
//
#include <hip/hip_runtime.h>

// Malvar-He-Cutler demosaic, RGGB, reflect-101, fp32.  FINAL (R10 revert).
// Lane-dense 4px/thread, shuffle halo, factorized vertical sums, NT stores.
//
// Performance ledger (8x2048x2048, MI355X):
//   R1 244us pair/thread -> R2 168 (8px/thread+XCD swizzle) -> R6 158 (plain
//   stores, factorized) -> R8 155 (lane-dense) -> R10 75.9 (NT stores).
// Key measured facts:
//   * NT stores with HALF-dense layout: 1.5x HBM write amplification (R5).
//     NT stores with lane-dense full-line coverage: no amplification, bypass
//     LLC allocation -> input stays LLC-resident, write drains at ~5.3+ TB/s.
//   * REPS=2 diagnostic (R9): doubling all loads+stores added ZERO time ->
//     purely traffic-bound; instruction count/ILP/latency irrelevant.
//   * Row-pair blocks (R11): 80us — regression; structural levers exhausted.

typedef float f4 __attribute__((ext_vector_type(4)));

__device__ __forceinline__ int reflect_idx(int i, int n) {
    // jnp.pad mode='reflect': -1 -> 1, -2 -> 2, n -> n-2, n+1 -> n-3
    if (i < 0) i = -i;
    if (i >= n) i = 2 * n - 2 - i;
    return i;
}

__device__ __forceinline__ float clip01(float x) {
    return fminf(fmaxf(x, 0.0f), 1.0f);
}

struct Halo { float m2, m1, p4, p5; };

__device__ __forceinline__ Halo make_halo(f4 x, f4 xl, f4 xr,
                                          bool lane0, bool lane63,
                                          bool ledge, bool redge) {
    Halo h;
    h.m2 = __shfl_up(x.z, 1);
    h.m1 = __shfl_up(x.w, 1);
    if (lane0) { h.m2 = xl.z; h.m1 = xl.w; }
    if (ledge) { h.m2 = x.z;  h.m1 = x.y; }   // col -2 -> 2, -1 -> 1
    h.p4 = __shfl_down(x.x, 1);
    h.p5 = __shfl_down(x.y, 1);
    if (lane63) { h.p4 = xr.x; h.p5 = xr.y; }
    if (redge)  { h.p4 = x.z;  h.p5 = x.y; }  // col W -> W-2, W+1 -> W-3
    return h;
}

template <bool EVEN_ROW>
__device__ __forceinline__ void compute4(
    const float C[8], const float S13[8], const float S04[8],
    float r[4], float g[4], float b[4]) {
#pragma unroll
    for (int k = 0; k < 4; k += 2) {
        const int c = 2 + k, o = 3 + k;
        const int ce = EVEN_ROW ? c : o;   // R/B raw-sample column
        const int co = EVEN_ROW ? o : c;   // G raw-sample column
        const float t2 = S04[ce] + C[ce - 2] + C[ce + 2];
        const float gatrb = 0.5f * C[ce]
                          + 0.25f * (S13[ce] + C[ce - 1] + C[ce + 1])
                          - 0.125f * t2;
        const float brv   = 0.75f * C[ce]
                          + 0.25f * (S13[ce - 1] + S13[ce + 1])
                          - 0.1875f * t2;
        const float t4 = C[co - 1] + C[co + 1];
        const float t5 = S13[co - 1] + S13[co + 1];
        const float t6 = C[co - 2] + C[co + 2];
        const float colv = 0.625f * C[co] + 0.5f * t4
                         - 0.125f * (t5 + t6) + 0.0625f * S04[co];
        const float rowv = 0.625f * C[co] + 0.5f * S13[co]
                         - 0.125f * t5 - 0.125f * S04[co] + 0.0625f * t6;
        if (EVEN_ROW) {
            r[k] = C[c];      g[k] = gatrb;      b[k] = brv;      // R site
            r[k + 1] = colv;  g[k + 1] = C[o];   b[k + 1] = rowv; // Gr site
        } else {
            r[k] = rowv;      g[k] = C[c];       b[k] = colv;     // Gb site
            r[k + 1] = brv;   g[k + 1] = gatrb;  b[k + 1] = C[o]; // B site
        }
    }
}

__global__ __launch_bounds__(256, 6) void demosaic_kernel(
    const float* __restrict__ bayer, float* __restrict__ out, int H, int W) {
    // XCD-chunked swizzle (gridDim.x divisible by 8): XCD k -> image k
    const int bid = blockIdx.x;
    const int chunk = gridDim.x >> 3;
    const int lin = (bid & 7) * chunk + (bid >> 3);
    const int XT = W >> 10;                 // 1024-px x-tiles per row
    const int xt = lin % XT;
    const int rowlin = lin / XT;
    const int y = rowlin % H;
    const int img = rowlin / H;

    const int tid = (int)threadIdx.x;
    const int lane = tid & 63;
    const bool lane0 = (lane == 0), lane63 = (lane == 63);
    const int x0 = xt * 1024 + (tid << 2);  // 4 px per thread, lane-dense
    const bool ledge = (x0 == 0);
    const bool redge = (x0 + 4 == W);

    const size_t plane = (size_t)H * W;
    const float* src = bayer + (size_t)img * plane;

    const float* rows[5];
#pragma unroll
    for (int i = 0; i < 5; ++i)
        rows[i] = src + (size_t)reflect_idx(y - 2 + i, H) * W;

    f4 a0 = *(const f4*)(rows[0] + x0);
    f4 a1 = *(const f4*)(rows[1] + x0);
    f4 a2 = *(const f4*)(rows[2] + x0);
    f4 a3 = *(const f4*)(rows[3] + x0);
    f4 a4 = *(const f4*)(rows[4] + x0);

    // wave-edge halo float4s (predicated)
    f4 LC = {0,0,0,0}, LS13 = {0,0,0,0}, LS04 = {0,0,0,0};
    f4 RC = {0,0,0,0}, RS13 = {0,0,0,0}, RS04 = {0,0,0,0};
    if (lane0 && !ledge) {
        f4 l0 = *(const f4*)(rows[0] + x0 - 4);
        f4 l1 = *(const f4*)(rows[1] + x0 - 4);
        f4 l2 = *(const f4*)(rows[2] + x0 - 4);
        f4 l3 = *(const f4*)(rows[3] + x0 - 4);
        f4 l4 = *(const f4*)(rows[4] + x0 - 4);
        LC = l2; LS13 = l1 + l3; LS04 = l0 + l4;
    }
    if (lane63 && !redge) {
        f4 r0 = *(const f4*)(rows[0] + x0 + 4);
        f4 r1 = *(const f4*)(rows[1] + x0 + 4);
        f4 r2 = *(const f4*)(rows[2] + x0 + 4);
        f4 r3 = *(const f4*)(rows[3] + x0 + 4);
        f4 r4 = *(const f4*)(rows[4] + x0 + 4);
        RC = r2; RS13 = r1 + r3; RS04 = r0 + r4;
    }

    // vertical sums (factorized stencils consume only these)
    const f4 Cc  = a2;
    const f4 S13 = a1 + a3;
    const f4 S04 = a0 + a4;

    const Halo hC  = make_halo(Cc,  LC,  RC,  lane0, lane63, ledge, redge);
    const Halo h13 = make_halo(S13, LS13, RS13, lane0, lane63, ledge, redge);
    const Halo h04 = make_halo(S04, LS04, RS04, lane0, lane63, ledge, redge);

    const float Cw[8]  = {hC.m2,  hC.m1,  Cc.x,  Cc.y,  Cc.z,  Cc.w,  hC.p4,  hC.p5};
    const float W13[8] = {h13.m2, h13.m1, S13.x, S13.y, S13.z, S13.w, h13.p4, h13.p5};
    const float W04[8] = {h04.m2, h04.m1, S04.x, S04.y, S04.z, S04.w, h04.p4, h04.p5};

    float r[4], g[4], b[4];
    if ((y & 1) == 0) compute4<true>(Cw, W13, W04, r, g, b);
    else              compute4<false>(Cw, W13, W04, r, g, b);

    float* o = out + (size_t)img * 3 * plane + (size_t)y * W + x0;
    f4 vr = {clip01(r[0]), clip01(r[1]), clip01(r[2]), clip01(r[3])};
    f4 vg = {clip01(g[0]), clip01(g[1]), clip01(g[2]), clip01(g[3])};
    f4 vb = {clip01(b[0]), clip01(b[1]), clip01(b[2]), clip01(b[3])};
    // NT stores: bypass LLC allocation; every 128B line fully covered per wave
    __builtin_nontemporal_store(vr, (f4*)(o));
    __builtin_nontemporal_store(vg, (f4*)(o + plane));
    __builtin_nontemporal_store(vb, (f4*)(o + 2 * plane));
}

extern "C" void kernel_launch(void* const* d_in, const int* in_sizes, int n_in,
                              void* d_out, int out_size, void* d_ws, size_t ws_size,
                              hipStream_t stream) {
    const float* bayer = (const float*)d_in[0];
    float* out = (float*)d_out;

    const int H = 2048, W = 2048;
    const int B = in_sizes[0] / (H * W);
    const int XT = W >> 10;  // 1024-px tiles

    dim3 block(256, 1, 1);
    dim3 grid(B * H * XT, 1, 1);
    demosaic_kernel<<<grid, block, 0, stream>>>(bayer, out, H, W);
}